// Round 5
// baseline (687.196 us; speedup 1.0000x reference)
//
#include <hip/hip_runtime.h>
#include <stdint.h>

#define D_MODEL 1024
#define NHEAD   16
#define BATCH   4
#define SEQ     2048
#define M_TOTAL 8192
#define R_ELEMS ((size_t)M_TOTAL * D_MODEL)    // 8388608 elems (16 MB bf16)
#define W_ELEMS ((size_t)D_MODEL * D_MODEL)    // 1048576 elems (2 MB bf16)

typedef short bf8_t __attribute__((ext_vector_type(8)));   // 8 bf16 = 4 VGPRs
typedef float f4_t  __attribute__((ext_vector_type(4)));   // 4 fp32 accum

#define MFMA16(a, b, c) __builtin_amdgcn_mfma_f32_16x16x32_bf16(a, b, c, 0, 0, 0)

// 1/sqrt(64) * log2(e): softmax computed in exp2 domain
#define SCALE_LOG2E 0.1803368801111244f

__device__ __forceinline__ unsigned short f2b(float f) {   // RNE
    union { float f; unsigned int u; } v; v.f = f;
    return (unsigned short)((v.u + 0x7fffu + ((v.u >> 16) & 1u)) >> 16);
}
__device__ __forceinline__ unsigned short f2b_fast(float f) {  // round-half-up (P only)
    union { float f; unsigned int u; } v; v.f = f;
    return (unsigned short)((v.u + 0x8000u) >> 16);
}

#if __has_builtin(__builtin_amdgcn_exp2f)
#define EXP2(x) __builtin_amdgcn_exp2f(x)
#else
#define EXP2(x) exp2f(x)
#endif

// async global->LDS, 16B per lane. LDS dest = wave-uniform base + lane*16.
__device__ __forceinline__ void async16(const unsigned short* g, unsigned short* l) {
    __builtin_amdgcn_global_load_lds(
        (const __attribute__((address_space(1))) unsigned int*)g,
        (__attribute__((address_space(3))) unsigned int*)l, 16, 0, 0);
}

// fp32 global -> 8 bf16 regs -> one 16B LDS store (VALU staging for weights)
__device__ __forceinline__ void cvt_store8(const float* __restrict__ g, unsigned short* l) {
    const float4 x = *(const float4*)g;
    const float4 y = *(const float4*)(g + 4);
    unsigned short t[8] = { f2b(x.x), f2b(x.y), f2b(x.z), f2b(x.w),
                            f2b(y.x), f2b(y.y), f2b(y.z), f2b(y.w) };
    *(uint4*)l = *(const uint4*)t;
}

// DPP cross-lane (row of 16) reductions — pure VALU, no LDS pipe.
template <int CTRL>
__device__ __forceinline__ float dppf(float x) {
    return __int_as_float(__builtin_amdgcn_mov_dpp(__float_as_int(x), CTRL, 0xf, 0xf, true));
}
__device__ __forceinline__ float rowmax16(float v) {
    v = fmaxf(v, dppf<0xB1>(v));    // quad_perm(1,0,3,2)
    v = fmaxf(v, dppf<0x4E>(v));    // quad_perm(2,3,0,1)
    v = fmaxf(v, dppf<0x141>(v));   // row_half_mirror
    v = fmaxf(v, dppf<0x140>(v));   // row_mirror
    return v;
}
__device__ __forceinline__ float rowsum16(float v) {
    v += dppf<0xB1>(v);
    v += dppf<0x4E>(v);
    v += dppf<0x141>(v);
    v += dppf<0x140>(v);
    return v;
}

// ---------------------------------------------------------------------------
// Merged fp32->bf16 convert: 3 input tensors (1M 8-elem groups each) then
// up to 4 weight tensors (128K groups each). Grid sized to exactly cover.
// ---------------------------------------------------------------------------
struct CvtArgs { const float* s[7]; unsigned short* d[7]; };

__global__ __launch_bounds__(256)
void cvt_multi(CvtArgs a) {
    const unsigned int gid = blockIdx.x * 256 + threadIdx.x;
    unsigned int t, i;
    if (gid < (3u << 20)) { t = gid >> 20; i = gid & ((1u << 20) - 1); }
    else { const unsigned int g = gid - (3u << 20); t = 3 + (g >> 17); i = g & ((1u << 17) - 1); }
    const float* s = a.s[t] + (size_t)i * 8;
    unsigned short* d = a.d[t] + (size_t)i * 8;
    const float4 x = *(const float4*)s;
    const float4 y = *(const float4*)(s + 4);
    unsigned short o[8] = { f2b(x.x), f2b(x.y), f2b(x.z), f2b(x.w),
                            f2b(y.x), f2b(y.y), f2b(y.z), f2b(y.w) };
    *(uint4*)d = *(const uint4*)o;
}

// ---------------------------------------------------------------------------
// GEMM tile body: out[m][n] = sum_k A[m][k]*W[n][k] + bias[n]  (K=1024)
// A bf16 via global_load_lds; W bf16-DMA (WF32=0) or fp32 VALU-cvt (WF32=1).
// 128x128 tile, BK=32, 4 waves 2x2 of 64x64. XOR-swizzled 16B LDS chunks.
// ol: 0 = bf16 head-major [b][h][s][64]; 1 = bf16 V-transposed [b][h][64][s];
//     2 = fp32 row-major [m][1024]
// ---------------------------------------------------------------------------
template<int WF32>
__device__ __forceinline__ void gemm_tile(const unsigned short* __restrict__ A,
                                          const void* __restrict__ Wp,
                                          const float* __restrict__ bias,
                                          void* __restrict__ outv,
                                          const int ol, const int m0, const int n0,
                                          unsigned short* As, unsigned short* Bs)
{
    const int tid  = threadIdx.x;
    const int lane = tid & 63;
    const int wave = tid >> 6;
    const int quad = lane >> 4;
    const int l16  = lane & 15;
    const int wm = (wave >> 1) * 64;
    const int wn = (wave & 1) * 64;

    f4_t acc[4][4];
#pragma unroll
    for (int i = 0; i < 4; ++i)
#pragma unroll
        for (int j = 0; j < 4; ++j)
            acc[i][j] = (f4_t){0.f, 0.f, 0.f, 0.f};

    for (int k0 = 0; k0 < 1024; k0 += 32) {
#pragma unroll
        for (int i = 0; i < 2; ++i) {
            const int s = tid + i * 256;             // LDS 16B slot
            const int r = s >> 2;                    // tile row
            const int c = (s & 3) ^ ((r >> 1) & 3);  // swizzled 16B chunk
            async16(A + (size_t)(m0 + r) * 1024 + k0 + c * 8, &As[s * 8]);
            if (WF32)
                cvt_store8((const float*)Wp + (size_t)(n0 + r) * 1024 + k0 + c * 8, &Bs[s * 8]);
            else
                async16((const unsigned short*)Wp + (size_t)(n0 + r) * 1024 + k0 + c * 8, &Bs[s * 8]);
        }
        __syncthreads();   // drains vmcnt (DMA) + lgkmcnt

        bf8_t af[4], bf[4];
#pragma unroll
        for (int mt = 0; mt < 4; ++mt) {
            const int rr = wm + mt * 16 + l16;
            af[mt] = *(const bf8_t*)&As[(rr * 4 + (quad ^ ((rr >> 1) & 3))) * 8];
        }
#pragma unroll
        for (int nt = 0; nt < 4; ++nt) {
            const int rr = wn + nt * 16 + l16;
            bf[nt] = *(const bf8_t*)&Bs[(rr * 4 + (quad ^ ((rr >> 1) & 3))) * 8];
        }
#pragma unroll
        for (int mt = 0; mt < 4; ++mt)
#pragma unroll
            for (int nt = 0; nt < 4; ++nt)
                acc[mt][nt] = MFMA16(af[mt], bf[nt], acc[mt][nt]);
        __syncthreads();
    }

    // Epilogue. C/D layout: col = lane&15, row = quad*4 + reg (m89-verified).
#pragma unroll
    for (int mt = 0; mt < 4; ++mt) {
#pragma unroll
        for (int nt = 0; nt < 4; ++nt) {
            const int nn = n0 + wn + nt * 16 + l16;
            const float bv = bias[nn];
            const int mbase = m0 + wm + mt * 16 + quad * 4;
            if (ol == 2) {
                float* of = (float*)outv;
#pragma unroll
                for (int r = 0; r < 4; ++r)
                    of[(size_t)(mbase + r) * 1024 + nn] = acc[mt][nt][r] + bv;
            } else if (ol == 0) {
                unsigned short* ob = (unsigned short*)outv;
                const int h = nn >> 6, d = nn & 63;
#pragma unroll
                for (int r = 0; r < 4; ++r) {
                    const int m = mbase + r;
                    const int b = m >> 11, s2 = m & 2047;
                    ob[((size_t)((b * 16 + h) * 2048 + s2) << 6) + d] = f2b(acc[mt][nt][r] + bv);
                }
            } else {
                // V transposed: [b][h][64][s]; 4 consecutive s -> one 8B store
                unsigned short* ob = (unsigned short*)outv;
                const int h = nn >> 6, d = nn & 63;
                const int b = mbase >> 11, s2 = mbase & 2047;
                unsigned short pk[4];
#pragma unroll
                for (int r = 0; r < 4; ++r) pk[r] = f2b(acc[mt][nt][r] + bv);
                *(uint2*)&ob[((size_t)((b * 16 + h) * 64 + d) << 11) + s2] = *(const uint2*)pk;
            }
        }
    }
}

template<int WF32>
__global__ __launch_bounds__(256, 2)
void qkv_gemm(const unsigned short* __restrict__ qb, const unsigned short* __restrict__ kb,
              const unsigned short* __restrict__ vb,
              const void* __restrict__ Wq, const void* __restrict__ Wk, const void* __restrict__ Wv,
              const float* __restrict__ bq, const float* __restrict__ bk, const float* __restrict__ bv,
              unsigned short* __restrict__ Qh, unsigned short* __restrict__ Kh,
              unsigned short* __restrict__ Vt)
{
    __shared__ unsigned short As[128 * 32];
    __shared__ unsigned short Bs[128 * 32];
    const int z = blockIdx.z;
    const unsigned short* A = (z == 0) ? qb : (z == 1) ? kb : vb;
    const void* W  = (z == 0) ? Wq : (z == 1) ? Wk : Wv;
    const float* bias = (z == 0) ? bq : (z == 1) ? bk : bv;
    void* out = (z == 0) ? (void*)Qh : (z == 1) ? (void*)Kh : (void*)Vt;
    gemm_tile<WF32>(A, W, bias, out, (z == 2) ? 1 : 0,
                    blockIdx.y * 128, blockIdx.x * 128, As, Bs);
}

template<int WF32>
__global__ __launch_bounds__(256, 2)
void o_gemm(const unsigned short* __restrict__ ctx, const void* __restrict__ Wo,
            const float* __restrict__ bo, float* __restrict__ out)
{
    __shared__ unsigned short As[128 * 32];
    __shared__ unsigned short Bs[128 * 32];
    gemm_tile<WF32>(ctx, Wo, bo, out, 2, blockIdx.y * 128, blockIdx.x * 128, As, Bs);
}

// ---------------------------------------------------------------------------
// Flash attention, causal, block-cooperative K/V staging.
// Block = 4 waves, ALL same (b,h). Wave w owns the balanced pair of 16-row
// q-tiles {j, 127-j}, j = jg*4+w. Per 64-key tile the block stages K (8KB)
// and V^T (8KB) into LDS via global_load_lds (XOR-swizzled 16B chunks),
// then each wave computes both its streams from LDS. bid = jg*64+bh so each
// bh's 16 blocks share an XCD (L2 locality). 2 barriers/iter.
// ---------------------------------------------------------------------------
__global__ __launch_bounds__(256, 4)
void attn_kernel(const unsigned short* __restrict__ Qh,
                 const unsigned short* __restrict__ Kh,
                 const unsigned short* __restrict__ Vt,
                 unsigned short* __restrict__ ctx)
{
    __shared__ unsigned short Ks[64 * 64];      // swizzled [row][8 chunks]
    __shared__ unsigned short Vs[64 * 64];      // swizzled [d][8 chunks of keys]
    __shared__ unsigned short Pw[8][16 * 72];   // per wave*2+stream

    const int tid  = threadIdx.x;
    const int lane = tid & 63;
    const int wave = tid >> 6;
    const int quad = lane >> 4;
    const int l16  = lane & 15;

    const int bid = blockIdx.x;       // jg*64 + bh
    const int bh  = bid & 63;
    const int jg  = bid >> 6;         // 0..15
    const int j   = jg * 4 + wave;    // 0..63

    const int qrow0[2] = { j * 16, (127 - j) * 16 };
    const int nkt[2] = { (qrow0[0] + 79) >> 6, (qrow0[1] + 79) >> 6 };
    const int nktmax = ((127 - jg * 4) * 16 + 79) >> 6;   // wave 0's nkt[1]

    bf8_t qf0[2], qf1[2];
#pragma unroll
    for (int s = 0; s < 2; ++s) {
        const unsigned short* qa = Qh + ((size_t)(bh * SEQ + qrow0[s] + l16) << 6);
        qf0[s] = *(const bf8_t*)(qa + quad * 8);
        qf1[s] = *(const bf8_t*)(qa + 32 + quad * 8);
    }

    float mrow[2][4], lrow[2][4];
    f4_t oacc[2][4];
#pragma unroll
    for (int s = 0; s < 2; ++s)
#pragma unroll
        for (int r = 0; r < 4; ++r) {
            mrow[s][r] = -1e30f; lrow[s][r] = 0.f;
            oacc[s][r] = (f4_t){0.f, 0.f, 0.f, 0.f};
        }

    unsigned short* pws[2] = { &Pw[wave * 2][0], &Pw[wave * 2 + 1][0] };

    for (int kt = 0; kt < nktmax; ++kt) {
        const int kb = kt * 64;

        // block-cooperative staging: 512 16B slots each for K and V^T
#pragma unroll
        for (int i2 = 0; i2 < 2; ++i2) {
            const int s = tid + i2 * 256;        // 0..511
            const int r = s >> 3;                // row (key for K, d for V)
            const int c = (s & 7) ^ (r & 7);     // swizzled 16B chunk
            async16(Kh + ((size_t)(bh * SEQ + kb + r) << 6) + c * 8, &Ks[s * 8]);
            async16(Vt + ((size_t)(bh * 64 + r) << 11) + kb + c * 8, &Vs[s * 8]);
        }
        __syncthreads();

        const bool act1 = (kt < nkt[1]);    // wave-uniform
        const bool act0 = (kt < nkt[0]);

        if (act1) {
            // QK^T for both streams, K fragments read once from LDS
            f4_t sacc[2][4];
#pragma unroll
            for (int nb = 0; nb < 4; ++nb) {
                const int rr = nb * 16 + l16;
                const bf8_t kf0 = *(const bf8_t*)&Ks[(rr * 8 + (quad ^ (rr & 7))) * 8];
                const bf8_t kf1 = *(const bf8_t*)&Ks[(rr * 8 + ((quad + 4) ^ (rr & 7))) * 8];
                f4_t s1 = (f4_t){0.f, 0.f, 0.f, 0.f};
                s1 = MFMA16(qf0[1], kf0, s1);
                s1 = MFMA16(qf1[1], kf1, s1);
                sacc[1][nb] = s1;
                if (act0) {
                    f4_t s0 = (f4_t){0.f, 0.f, 0.f, 0.f};
                    s0 = MFMA16(qf0[0], kf0, s0);
                    s0 = MFMA16(qf1[0], kf1, s0);
                    sacc[0][nb] = s0;
                }
            }

            // V^T B-fragments from LDS (shared by both streams)
            bf8_t vfa[4], vfb[4];
#pragma unroll
            for (int d4 = 0; d4 < 4; ++d4) {
                const int rr = d4 * 16 + l16;
                vfa[d4] = *(const bf8_t*)&Vs[(rr * 8 + (quad ^ (rr & 7))) * 8];
                vfb[d4] = *(const bf8_t*)&Vs[(rr * 8 + ((quad + 4) ^ (rr & 7))) * 8];
            }

            // softmax + P store per stream
#pragma unroll
            for (int s = 0; s < 2; ++s) {
                if (s == 0 && !act0) continue;
                const bool diag = (kt == nkt[s] - 1);   // wave-uniform
                float sv[4][4];
#pragma unroll
                for (int nb = 0; nb < 4; ++nb) {
                    const int kcol = kb + nb * 16 + l16;
#pragma unroll
                    for (int r = 0; r < 4; ++r) {
                        const float x = sacc[s][nb][r] * SCALE_LOG2E;
                        sv[nb][r] = (!diag || kcol <= qrow0[s] + quad * 4 + r) ? x : -1e30f;
                    }
                }
                float p[4][4];
#pragma unroll
                for (int r = 0; r < 4; ++r) {
                    float v = fmaxf(fmaxf(sv[0][r], sv[1][r]), fmaxf(sv[2][r], sv[3][r]));
                    v = rowmax16(v);
                    const float mnew = fmaxf(mrow[s][r], v);
                    const float alpha = EXP2(mrow[s][r] - mnew);
                    mrow[s][r] = mnew;
                    float rs = 0.f;
#pragma unroll
                    for (int nb = 0; nb < 4; ++nb) {
                        p[nb][r] = EXP2(sv[nb][r] - mnew);
                        rs += p[nb][r];
                    }
                    rs = rowsum16(rs);
                    lrow[s][r] = alpha * lrow[s][r] + rs;
#pragma unroll
                    for (int d4 = 0; d4 < 4; ++d4)
                        oacc[s][d4][r] *= alpha;
                }
#pragma unroll
                for (int nb = 0; nb < 4; ++nb)
#pragma unroll
                    for (int r = 0; r < 4; ++r)
                        pws[s][(quad * 4 + r) * 72 + nb * 16 + l16] = f2b_fast(p[nb][r]);
            }

            asm volatile("s_waitcnt lgkmcnt(0)" ::: "memory");   // in-wave LDS fence

            // O += P(16x64) . V(64x64)
            {
                const bf8_t pf0 = *(const bf8_t*)&pws[1][l16 * 72 + quad * 8];
                const bf8_t pf1 = *(const bf8_t*)&pws[1][l16 * 72 + 32 + quad * 8];
#pragma unroll
                for (int d4 = 0; d4 < 4; ++d4) {
                    oacc[1][d4] = MFMA16(pf0, vfa[d4], oacc[1][d4]);
                    oacc[1][d4] = MFMA16(pf1, vfb[d4], oacc[1][d4]);
                }
            }
            if (act0) {
                const bf8_t pf0 = *(const bf8_t*)&pws[0][l16 * 72 + quad * 8];
                const bf8_t pf1 = *(const bf8_t*)&pws[0][l16 * 72 + 32 + quad * 8];
#pragma unroll
                for (int d4 = 0; d4 < 4; ++d4) {
                    oacc[0][d4] = MFMA16(pf0, vfa[d4], oacc[0][d4]);
                    oacc[0][d4] = MFMA16(pf1, vfb[d4], oacc[0][d4]);
                }
            }
        }
        __syncthreads();   // protect Ks/Vs before next stage
    }

    // normalize, write ctx [b][s][1024] (head h at col h*64)
    const int b = bh >> 4, h = bh & 15;
#pragma unroll
    for (int s = 0; s < 2; ++s)
#pragma unroll
        for (int r = 0; r < 4; ++r) {
            const float inv = 1.f / lrow[s][r];
            const int qr = qrow0[s] + quad * 4 + r;
            unsigned short* cb = ctx + ((size_t)(b * SEQ + qr) << 10) + h * 64;
#pragma unroll
            for (int d4 = 0; d4 < 4; ++d4)
                cb[d4 * 16 + l16] = f2b(oacc[s][d4][r] * inv);
        }
}

// ---------------------------------------------------------------------------
extern "C" void kernel_launch(void* const* d_in, const int* in_sizes, int n_in,
                              void* d_out, int out_size, void* d_ws, size_t ws_size,
                              hipStream_t stream) {
    const float* q_in = (const float*)d_in[0];
    const float* k_in = (const float*)d_in[1];
    const float* v_in = (const float*)d_in[2];
    // d_in[3]: mask — fixed causal tril; hard-coded in attn_kernel.
    const float* Wq = (const float*)d_in[4];
    const float* bq = (const float*)d_in[5];
    const float* Wk = (const float*)d_in[6];
    const float* bk = (const float*)d_in[7];
    const float* Wv = (const float*)d_in[8];
    const float* bv = (const float*)d_in[9];
    const float* Wo = (const float*)d_in[10];
    const float* bo = (const float*)d_in[11];

    // ws (>=64MiB): Qh | Kh | Vt | X   (X = v_bf16, later ctx)
    // d_out (32MB fp32, dead until final GEMM): q_bf16 | k_bf16
    unsigned short* w  = (unsigned short*)d_ws;
    unsigned short* Qh = w;
    unsigned short* Kh = w + R_ELEMS;
    unsigned short* Vt = w + 2 * R_ELEMS;
    unsigned short* X  = w + 3 * R_ELEMS;
    unsigned short* qb = (unsigned short*)d_out;
    unsigned short* kb = qb + R_ELEMS;

    const dim3 gb(256);
    const size_t need_big = (4 * R_ELEMS + 4 * W_ELEMS) * 2;   // 72 MB

    CvtArgs ca;
    ca.s[0] = q_in; ca.d[0] = qb;
    ca.s[1] = k_in; ca.d[1] = kb;
    ca.s[2] = v_in; ca.d[2] = X;

    if (ws_size >= need_big) {
        // room for pre-converted bf16 weights -> pure-DMA GEMMs
        unsigned short* wb = w + 4 * R_ELEMS;
        ca.s[3] = Wq; ca.d[3] = wb;
        ca.s[4] = Wk; ca.d[4] = wb + W_ELEMS;
        ca.s[5] = Wv; ca.d[5] = wb + 2 * W_ELEMS;
        ca.s[6] = Wo; ca.d[6] = wb + 3 * W_ELEMS;
        cvt_multi<<<14336, gb, 0, stream>>>(ca);
        qkv_gemm<0><<<dim3(8, 64, 3), gb, 0, stream>>>(qb, kb, X, wb, wb + W_ELEMS,
                                                       wb + 2 * W_ELEMS, bq, bk, bv, Qh, Kh, Vt);
        attn_kernel<<<dim3(1024), gb, 0, stream>>>(Qh, Kh, Vt, X);
        o_gemm<0><<<dim3(8, 64), gb, 0, stream>>>(X, wb + 3 * W_ELEMS, bo, (float*)d_out);
    } else {
        // 64 MiB ws: weights stay fp32, staged via VALU cvt inside the GEMM
        ca.s[3] = Wq; ca.d[3] = qb;  // unused entries (grid stops at 3M groups)
        ca.s[4] = Wk; ca.d[4] = qb;
        ca.s[5] = Wv; ca.d[5] = qb;
        ca.s[6] = Wo; ca.d[6] = qb;
        cvt_multi<<<12288, gb, 0, stream>>>(ca);
        qkv_gemm<1><<<dim3(8, 64, 3), gb, 0, stream>>>(qb, kb, X, Wq, Wk, Wv,
                                                       bq, bk, bv, Qh, Kh, Vt);
        attn_kernel<<<dim3(1024), gb, 0, stream>>>(Qh, Kh, Vt, X);
        o_gemm<1><<<dim3(8, 64), gb, 0, stream>>>(X, Wo, bo, (float*)d_out);
    }
}

// Round 6
// 397.551 us; speedup vs baseline: 1.7286x; 1.7286x over previous
//
#include <hip/hip_runtime.h>
#include <stdint.h>

#define D_MODEL 1024
#define NHEAD   16
#define BATCH   4
#define SEQ     2048
#define M_TOTAL 8192
#define R_ELEMS ((size_t)M_TOTAL * D_MODEL)    // 8388608 elems (16 MB bf16)
#define W_ELEMS ((size_t)D_MODEL * D_MODEL)    // 1048576 elems (2 MB bf16)

typedef short bf8_t __attribute__((ext_vector_type(8)));   // 8 bf16 = 4 VGPRs
typedef float f4_t  __attribute__((ext_vector_type(4)));   // 4 fp32 accum

#define MFMA16(a, b, c) __builtin_amdgcn_mfma_f32_16x16x32_bf16(a, b, c, 0, 0, 0)

// 1/sqrt(64) * log2(e): softmax computed in exp2 domain
#define SCALE_LOG2E 0.1803368801111244f

__device__ __forceinline__ unsigned short f2b(float f) {   // RNE
    union { float f; unsigned int u; } v; v.f = f;
    return (unsigned short)((v.u + 0x7fffu + ((v.u >> 16) & 1u)) >> 16);
}
__device__ __forceinline__ unsigned short f2b_fast(float f) {  // round-half-up (P only)
    union { float f; unsigned int u; } v; v.f = f;
    return (unsigned short)((v.u + 0x8000u) >> 16);
}

#if __has_builtin(__builtin_amdgcn_exp2f)
#define EXP2(x) __builtin_amdgcn_exp2f(x)
#else
#define EXP2(x) exp2f(x)
#endif

// async global->LDS, 16B per lane. LDS dest = wave-uniform base + lane*16.
__device__ __forceinline__ void async16(const unsigned short* g, unsigned short* l) {
    __builtin_amdgcn_global_load_lds(
        (const __attribute__((address_space(1))) unsigned int*)g,
        (__attribute__((address_space(3))) unsigned int*)l, 16, 0, 0);
}

// fp32 global -> 8 bf16 regs -> one 16B LDS store (VALU staging for weights)
__device__ __forceinline__ void cvt_store8(const float* __restrict__ g, unsigned short* l) {
    const float4 x = *(const float4*)g;
    const float4 y = *(const float4*)(g + 4);
    unsigned short t[8] = { f2b(x.x), f2b(x.y), f2b(x.z), f2b(x.w),
                            f2b(y.x), f2b(y.y), f2b(y.z), f2b(y.w) };
    *(uint4*)l = *(const uint4*)t;
}

// DPP cross-lane (row of 16) reductions — pure VALU, no LDS pipe.
template <int CTRL>
__device__ __forceinline__ float dppf(float x) {
    return __int_as_float(__builtin_amdgcn_mov_dpp(__float_as_int(x), CTRL, 0xf, 0xf, true));
}
__device__ __forceinline__ float rowmax16(float v) {
    v = fmaxf(v, dppf<0xB1>(v));    // quad_perm(1,0,3,2)
    v = fmaxf(v, dppf<0x4E>(v));    // quad_perm(2,3,0,1)
    v = fmaxf(v, dppf<0x141>(v));   // row_half_mirror
    v = fmaxf(v, dppf<0x140>(v));   // row_mirror
    return v;
}
__device__ __forceinline__ float rowsum16(float v) {
    v += dppf<0xB1>(v);
    v += dppf<0x4E>(v);
    v += dppf<0x141>(v);
    v += dppf<0x140>(v);
    return v;
}

// ---------------------------------------------------------------------------
// Merged fp32->bf16 convert: 3 input tensors (1M 8-elem groups each) then
// up to 4 weight tensors (128K groups each). Grid sized to exactly cover.
// ---------------------------------------------------------------------------
struct CvtArgs { const float* s[7]; unsigned short* d[7]; };

__global__ __launch_bounds__(256)
void cvt_multi(CvtArgs a) {
    const unsigned int gid = blockIdx.x * 256 + threadIdx.x;
    unsigned int t, i;
    if (gid < (3u << 20)) { t = gid >> 20; i = gid & ((1u << 20) - 1); }
    else { const unsigned int g = gid - (3u << 20); t = 3 + (g >> 17); i = g & ((1u << 17) - 1); }
    const float* s = a.s[t] + (size_t)i * 8;
    unsigned short* d = a.d[t] + (size_t)i * 8;
    const float4 x = *(const float4*)s;
    const float4 y = *(const float4*)(s + 4);
    unsigned short o[8] = { f2b(x.x), f2b(x.y), f2b(x.z), f2b(x.w),
                            f2b(y.x), f2b(y.y), f2b(y.z), f2b(y.w) };
    *(uint4*)d = *(const uint4*)o;
}

// ---------------------------------------------------------------------------
// GEMM tile body: out[m][n] = sum_k A[m][k]*W[n][k] + bias[n]  (K=1024)
// A bf16 via global_load_lds; W bf16-DMA (WF32=0) or fp32 VALU-cvt (WF32=1).
// 128x128 tile, BK=32, 4 waves 2x2 of 64x64. XOR-swizzled 16B LDS chunks.
// ol: 0 = bf16 head-major [b][h][s][64]; 1 = bf16 V-transposed [b][h][64][s];
//     2 = fp32 row-major [m][1024]
// ---------------------------------------------------------------------------
template<int WF32>
__device__ __forceinline__ void gemm_tile(const unsigned short* __restrict__ A,
                                          const void* __restrict__ Wp,
                                          const float* __restrict__ bias,
                                          void* __restrict__ outv,
                                          const int ol, const int m0, const int n0,
                                          unsigned short* As, unsigned short* Bs)
{
    const int tid  = threadIdx.x;
    const int lane = tid & 63;
    const int wave = tid >> 6;
    const int quad = lane >> 4;
    const int l16  = lane & 15;
    const int wm = (wave >> 1) * 64;
    const int wn = (wave & 1) * 64;

    f4_t acc[4][4];
#pragma unroll
    for (int i = 0; i < 4; ++i)
#pragma unroll
        for (int j = 0; j < 4; ++j)
            acc[i][j] = (f4_t){0.f, 0.f, 0.f, 0.f};

    for (int k0 = 0; k0 < 1024; k0 += 32) {
#pragma unroll
        for (int i = 0; i < 2; ++i) {
            const int s = tid + i * 256;             // LDS 16B slot
            const int r = s >> 2;                    // tile row
            const int c = (s & 3) ^ ((r >> 1) & 3);  // swizzled 16B chunk
            async16(A + (size_t)(m0 + r) * 1024 + k0 + c * 8, &As[s * 8]);
            if (WF32)
                cvt_store8((const float*)Wp + (size_t)(n0 + r) * 1024 + k0 + c * 8, &Bs[s * 8]);
            else
                async16((const unsigned short*)Wp + (size_t)(n0 + r) * 1024 + k0 + c * 8, &Bs[s * 8]);
        }
        __syncthreads();   // drains vmcnt (DMA) + lgkmcnt

        bf8_t af[4], bf[4];
#pragma unroll
        for (int mt = 0; mt < 4; ++mt) {
            const int rr = wm + mt * 16 + l16;
            af[mt] = *(const bf8_t*)&As[(rr * 4 + (quad ^ ((rr >> 1) & 3))) * 8];
        }
#pragma unroll
        for (int nt = 0; nt < 4; ++nt) {
            const int rr = wn + nt * 16 + l16;
            bf[nt] = *(const bf8_t*)&Bs[(rr * 4 + (quad ^ ((rr >> 1) & 3))) * 8];
        }
#pragma unroll
        for (int mt = 0; mt < 4; ++mt)
#pragma unroll
            for (int nt = 0; nt < 4; ++nt)
                acc[mt][nt] = MFMA16(af[mt], bf[nt], acc[mt][nt]);
        __syncthreads();
    }

    // Epilogue. C/D layout: col = lane&15, row = quad*4 + reg (m89-verified).
#pragma unroll
    for (int mt = 0; mt < 4; ++mt) {
#pragma unroll
        for (int nt = 0; nt < 4; ++nt) {
            const int nn = n0 + wn + nt * 16 + l16;
            const float bv = bias[nn];
            const int mbase = m0 + wm + mt * 16 + quad * 4;
            if (ol == 2) {
                float* of = (float*)outv;
#pragma unroll
                for (int r = 0; r < 4; ++r)
                    of[(size_t)(mbase + r) * 1024 + nn] = acc[mt][nt][r] + bv;
            } else if (ol == 0) {
                unsigned short* ob = (unsigned short*)outv;
                const int h = nn >> 6, d = nn & 63;
#pragma unroll
                for (int r = 0; r < 4; ++r) {
                    const int m = mbase + r;
                    const int b = m >> 11, s2 = m & 2047;
                    ob[((size_t)((b * 16 + h) * 2048 + s2) << 6) + d] = f2b(acc[mt][nt][r] + bv);
                }
            } else {
                // V transposed: [b][h][64][s]; 4 consecutive s -> one 8B store
                unsigned short* ob = (unsigned short*)outv;
                const int h = nn >> 6, d = nn & 63;
                const int b = mbase >> 11, s2 = mbase & 2047;
                unsigned short pk[4];
#pragma unroll
                for (int r = 0; r < 4; ++r) pk[r] = f2b(acc[mt][nt][r] + bv);
                *(uint2*)&ob[((size_t)((b * 16 + h) * 64 + d) << 11) + s2] = *(const uint2*)pk;
            }
        }
    }
}

template<int WF32>
__global__ __launch_bounds__(256, 2)
void qkv_gemm(const unsigned short* __restrict__ qb, const unsigned short* __restrict__ kb,
              const unsigned short* __restrict__ vb,
              const void* __restrict__ Wq, const void* __restrict__ Wk, const void* __restrict__ Wv,
              const float* __restrict__ bq, const float* __restrict__ bk, const float* __restrict__ bv,
              unsigned short* __restrict__ Qh, unsigned short* __restrict__ Kh,
              unsigned short* __restrict__ Vt)
{
    __shared__ unsigned short As[128 * 32];
    __shared__ unsigned short Bs[128 * 32];
    const int z = blockIdx.z;
    const unsigned short* A = (z == 0) ? qb : (z == 1) ? kb : vb;
    const void* W  = (z == 0) ? Wq : (z == 1) ? Wk : Wv;
    const float* bias = (z == 0) ? bq : (z == 1) ? bk : bv;
    void* out = (z == 0) ? (void*)Qh : (z == 1) ? (void*)Kh : (void*)Vt;
    gemm_tile<WF32>(A, W, bias, out, (z == 2) ? 1 : 0,
                    blockIdx.y * 128, blockIdx.x * 128, As, Bs);
}

template<int WF32>
__global__ __launch_bounds__(256, 2)
void o_gemm(const unsigned short* __restrict__ ctx, const void* __restrict__ Wo,
            const float* __restrict__ bo, float* __restrict__ out)
{
    __shared__ unsigned short As[128 * 32];
    __shared__ unsigned short Bs[128 * 32];
    gemm_tile<WF32>(ctx, Wo, bo, out, 2, blockIdx.y * 128, blockIdx.x * 128, As, Bs);
}

// ---------------------------------------------------------------------------
// Flash attention, causal, block-cooperative K/V staging.
// Block = 4 waves, ALL same (b,h). Wave w owns the balanced pair of 16-row
// q-tiles {j, 127-j}, j = jg*4+w. Per 64-key tile the block stages K (8KB)
// and V^T (8KB) into LDS via global_load_lds (XOR-swizzled 16B chunks),
// then each wave computes its streams from LDS. bid = jg*64+bh keeps each
// bh's 16 blocks on one XCD. 2 barriers/iter.
// REGISTER BUDGET: launch_bounds(256,2) -> 128 VGPR cap. Streams processed
// sequentially (one sacc/sv/p live at a time); V-fragments read from LDS at
// MFMA time, not prefetched. R5's (256,4) capped VGPR at 64 -> inner-loop
// scratch spills -> 918 MB WRITE_SIZE, 404 us. Do not tighten again.
// ---------------------------------------------------------------------------
__global__ __launch_bounds__(256, 2)
void attn_kernel(const unsigned short* __restrict__ Qh,
                 const unsigned short* __restrict__ Kh,
                 const unsigned short* __restrict__ Vt,
                 unsigned short* __restrict__ ctx)
{
    __shared__ unsigned short Ks[64 * 64];      // swizzled [row][8 chunks]
    __shared__ unsigned short Vs[64 * 64];      // swizzled [d][8 chunks of keys]
    __shared__ unsigned short Pw[8][16 * 72];   // per wave*2+stream

    const int tid  = threadIdx.x;
    const int lane = tid & 63;
    const int wave = tid >> 6;
    const int quad = lane >> 4;
    const int l16  = lane & 15;

    const int bid = blockIdx.x;       // jg*64 + bh
    const int bh  = bid & 63;
    const int jg  = bid >> 6;         // 0..15
    const int j   = jg * 4 + wave;    // 0..63

    const int qrow0[2] = { j * 16, (127 - j) * 16 };
    const int nkt[2] = { (qrow0[0] + 79) >> 6, (qrow0[1] + 79) >> 6 };
    const int nktmax = ((127 - jg * 4) * 16 + 79) >> 6;   // wave 0's nkt[1]

    bf8_t qf0[2], qf1[2];
#pragma unroll
    for (int s = 0; s < 2; ++s) {
        const unsigned short* qa = Qh + ((size_t)(bh * SEQ + qrow0[s] + l16) << 6);
        qf0[s] = *(const bf8_t*)(qa + quad * 8);
        qf1[s] = *(const bf8_t*)(qa + 32 + quad * 8);
    }

    float mrow[2][4], lrow[2][4];
    f4_t oacc[2][4];
#pragma unroll
    for (int s = 0; s < 2; ++s)
#pragma unroll
        for (int r = 0; r < 4; ++r) {
            mrow[s][r] = -1e30f; lrow[s][r] = 0.f;
            oacc[s][r] = (f4_t){0.f, 0.f, 0.f, 0.f};
        }

    for (int kt = 0; kt < nktmax; ++kt) {
        const int kb = kt * 64;

        // block-cooperative staging: 512 16B slots each for K and V^T
#pragma unroll
        for (int i2 = 0; i2 < 2; ++i2) {
            const int s = tid + i2 * 256;        // 0..511
            const int r = s >> 3;                // row (key for K, d for V)
            const int c = (s & 7) ^ (r & 7);     // swizzled 16B chunk
            async16(Kh + ((size_t)(bh * SEQ + kb + r) << 6) + c * 8, &Ks[s * 8]);
            async16(Vt + ((size_t)(bh * 64 + r) << 11) + kb + c * 8, &Vs[s * 8]);
        }
        __syncthreads();

        // streams processed SEQUENTIALLY to cap register pressure
#pragma unroll
        for (int s = 1; s >= 0; --s) {
            if (kt >= nkt[s]) continue;          // wave-uniform
            // QK^T from LDS
            f4_t sacc[4];
#pragma unroll
            for (int nb = 0; nb < 4; ++nb) {
                const int rr = nb * 16 + l16;
                const bf8_t kf0 = *(const bf8_t*)&Ks[(rr * 8 + (quad ^ (rr & 7))) * 8];
                const bf8_t kf1 = *(const bf8_t*)&Ks[(rr * 8 + ((quad + 4) ^ (rr & 7))) * 8];
                f4_t sc = (f4_t){0.f, 0.f, 0.f, 0.f};
                sc = MFMA16(qf0[s], kf0, sc);
                sc = MFMA16(qf1[s], kf1, sc);
                sacc[nb] = sc;
            }
            const bool diag = (kt == nkt[s] - 1);   // wave-uniform
            float sv[4][4];
#pragma unroll
            for (int nb = 0; nb < 4; ++nb) {
                const int kcol = kb + nb * 16 + l16;
#pragma unroll
                for (int r = 0; r < 4; ++r) {
                    const float x = sacc[nb][r] * SCALE_LOG2E;
                    sv[nb][r] = (!diag || kcol <= qrow0[s] + quad * 4 + r) ? x : -1e30f;
                }
            }
#pragma unroll
            for (int r = 0; r < 4; ++r) {
                float v = fmaxf(fmaxf(sv[0][r], sv[1][r]), fmaxf(sv[2][r], sv[3][r]));
                v = rowmax16(v);
                const float mnew = fmaxf(mrow[s][r], v);
                const float alpha = EXP2(mrow[s][r] - mnew);
                mrow[s][r] = mnew;
                float rs = 0.f;
#pragma unroll
                for (int nb = 0; nb < 4; ++nb) {
                    sv[nb][r] = EXP2(sv[nb][r] - mnew);   // sv becomes p
                    rs += sv[nb][r];
                }
                rs = rowsum16(rs);
                lrow[s][r] = alpha * lrow[s][r] + rs;
#pragma unroll
                for (int d4 = 0; d4 < 4; ++d4)
                    oacc[s][d4][r] *= alpha;
            }
            unsigned short* pws = &Pw[wave * 2 + s][0];
#pragma unroll
            for (int nb = 0; nb < 4; ++nb)
#pragma unroll
                for (int r = 0; r < 4; ++r)
                    pws[(quad * 4 + r) * 72 + nb * 16 + l16] = f2b_fast(sv[nb][r]);

            asm volatile("s_waitcnt lgkmcnt(0)" ::: "memory");   // in-wave fence

            // O += P(16x64) . V(64x64); V-fragments from LDS at use time
            const bf8_t pf0 = *(const bf8_t*)&pws[l16 * 72 + quad * 8];
            const bf8_t pf1 = *(const bf8_t*)&pws[l16 * 72 + 32 + quad * 8];
#pragma unroll
            for (int d4 = 0; d4 < 4; ++d4) {
                const int rr = d4 * 16 + l16;
                const bf8_t vfa = *(const bf8_t*)&Vs[(rr * 8 + (quad ^ (rr & 7))) * 8];
                const bf8_t vfb = *(const bf8_t*)&Vs[(rr * 8 + ((quad + 4) ^ (rr & 7))) * 8];
                oacc[s][d4] = MFMA16(pf0, vfa, oacc[s][d4]);
                oacc[s][d4] = MFMA16(pf1, vfb, oacc[s][d4]);
            }
        }
        __syncthreads();   // protect Ks/Vs before next stage
    }

    // normalize, write ctx [b][s][1024] (head h at col h*64)
    const int b = bh >> 4, h = bh & 15;
#pragma unroll
    for (int s = 0; s < 2; ++s)
#pragma unroll
        for (int r = 0; r < 4; ++r) {
            const float inv = 1.f / lrow[s][r];
            const int qr = qrow0[s] + quad * 4 + r;
            unsigned short* cb = ctx + ((size_t)(b * SEQ + qr) << 10) + h * 64;
#pragma unroll
            for (int d4 = 0; d4 < 4; ++d4)
                cb[d4 * 16 + l16] = f2b(oacc[s][d4][r] * inv);
        }
}

// ---------------------------------------------------------------------------
extern "C" void kernel_launch(void* const* d_in, const int* in_sizes, int n_in,
                              void* d_out, int out_size, void* d_ws, size_t ws_size,
                              hipStream_t stream) {
    const float* q_in = (const float*)d_in[0];
    const float* k_in = (const float*)d_in[1];
    const float* v_in = (const float*)d_in[2];
    // d_in[3]: mask — fixed causal tril; hard-coded in attn_kernel.
    const float* Wq = (const float*)d_in[4];
    const float* bq = (const float*)d_in[5];
    const float* Wk = (const float*)d_in[6];
    const float* bk = (const float*)d_in[7];
    const float* Wv = (const float*)d_in[8];
    const float* bv = (const float*)d_in[9];
    const float* Wo = (const float*)d_in[10];
    const float* bo = (const float*)d_in[11];

    // ws (>=64MiB): Qh | Kh | Vt | X   (X = v_bf16, later ctx)
    // d_out (32MB fp32, dead until final GEMM): q_bf16 | k_bf16
    unsigned short* w  = (unsigned short*)d_ws;
    unsigned short* Qh = w;
    unsigned short* Kh = w + R_ELEMS;
    unsigned short* Vt = w + 2 * R_ELEMS;
    unsigned short* X  = w + 3 * R_ELEMS;
    unsigned short* qb = (unsigned short*)d_out;
    unsigned short* kb = qb + R_ELEMS;

    const dim3 gb(256);
    const size_t need_big = (4 * R_ELEMS + 4 * W_ELEMS) * 2;   // 72 MB

    CvtArgs ca;
    ca.s[0] = q_in; ca.d[0] = qb;
    ca.s[1] = k_in; ca.d[1] = kb;
    ca.s[2] = v_in; ca.d[2] = X;

    if (ws_size >= need_big) {
        // room for pre-converted bf16 weights -> pure-DMA GEMMs
        unsigned short* wb = w + 4 * R_ELEMS;
        ca.s[3] = Wq; ca.d[3] = wb;
        ca.s[4] = Wk; ca.d[4] = wb + W_ELEMS;
        ca.s[5] = Wv; ca.d[5] = wb + 2 * W_ELEMS;
        ca.s[6] = Wo; ca.d[6] = wb + 3 * W_ELEMS;
        cvt_multi<<<14336, gb, 0, stream>>>(ca);
        qkv_gemm<0><<<dim3(8, 64, 3), gb, 0, stream>>>(qb, kb, X, wb, wb + W_ELEMS,
                                                       wb + 2 * W_ELEMS, bq, bk, bv, Qh, Kh, Vt);
        attn_kernel<<<dim3(1024), gb, 0, stream>>>(Qh, Kh, Vt, X);
        o_gemm<0><<<dim3(8, 64), gb, 0, stream>>>(X, wb + 3 * W_ELEMS, bo, (float*)d_out);
    } else {
        // 64 MiB ws: weights stay fp32, staged via VALU cvt inside the GEMM
        ca.s[3] = Wq; ca.d[3] = qb;  // unused entries (grid stops at 3M groups)
        ca.s[4] = Wk; ca.d[4] = qb;
        ca.s[5] = Wv; ca.d[5] = qb;
        ca.s[6] = Wo; ca.d[6] = qb;
        cvt_multi<<<12288, gb, 0, stream>>>(ca);
        qkv_gemm<1><<<dim3(8, 64, 3), gb, 0, stream>>>(qb, kb, X, Wq, Wk, Wv,
                                                       bq, bk, bv, Qh, Kh, Vt);
        attn_kernel<<<dim3(1024), gb, 0, stream>>>(Qh, Kh, Vt, X);
        o_gemm<1><<<dim3(8, 64), gb, 0, stream>>>(X, Wo, bo, (float*)d_out);
    }
}